// Round 1
// baseline (459.581 us; speedup 1.0000x reference)
//
#include <hip/hip_runtime.h>
#include <math.h>

// Problem constants (from reference)
constexpr int NN  = 100000;  // nodes
constexpr int DIN = 128;
constexpr int DH  = 16;      // hidden
constexpr int NC  = 40;      // classes

// ---------------- kernels ----------------

__global__ void k_zero(float* __restrict__ p, int n) {
    int i  = blockIdx.x * blockDim.x + threadIdx.x;
    int st = gridDim.x * blockDim.x;
    for (; i < n; i += st) p[i] = 0.0f;
}

__global__ void k_degree(const int* __restrict__ dst, int E, int* __restrict__ deg) {
    int i  = blockIdx.x * blockDim.x + threadIdx.x;
    int st = gridDim.x * blockDim.x;
    for (; i < E; i += st) atomicAdd(deg + dst[i], 1);
}

// p1l = x @ W1l, p1r = x @ W1r   (fused: x read once)
// thread per (node, j), j in [0,32): j<16 -> W1l col j, else W1r col j-16
__global__ void k_proj1(const float* __restrict__ x,
                        const float* __restrict__ W1l,
                        const float* __restrict__ W1r,
                        float* __restrict__ p1l,
                        float* __restrict__ p1r) {
    __shared__ float sW[2 * DIN * DH];  // 16 KB: W1l then W1r, both [128][16]
    for (int i = threadIdx.x; i < DIN * DH; i += blockDim.x) {
        sW[i]            = W1l[i];
        sW[DIN * DH + i] = W1r[i];
    }
    __syncthreads();
    long gid   = (long)blockIdx.x * blockDim.x + threadIdx.x;
    long total = (long)NN * 32;
    long st    = (long)gridDim.x * blockDim.x;
    for (; gid < total; gid += st) {
        int n = (int)(gid >> 5);
        int j = (int)(gid & 31);
        const float* w  = (j < DH) ? (sW + j) : (sW + DIN * DH + (j - DH));
        const float* xr = x + (long)n * DIN;
        float acc = 0.0f;
        #pragma unroll 8
        for (int k = 0; k < DIN; ++k) acc = fmaf(xr[k], w[k * DH], acc);
        if (j < DH) p1l[n * DH + j]        = acc;
        else        p1r[n * DH + (j - DH)] = acc;
    }
}

// agg[dst[e]*16+d] += val[src[e]*16+d], thread per (edge, d)
__global__ void k_scatter16(const int* __restrict__ src, const int* __restrict__ dst,
                            int E, const float* __restrict__ val,
                            float* __restrict__ agg) {
    long gid   = (long)blockIdx.x * blockDim.x + threadIdx.x;
    long total = (long)E * DH;
    long st    = (long)gridDim.x * blockDim.x;
    for (; gid < total; gid += st) {
        int e = (int)(gid >> 4);
        int d = (int)(gid & 15);
        atomicAdd(agg + (long)dst[e] * DH + d, val[(long)src[e] * DH + d]);
    }
}

// h = relu(agg1/max(deg,1) + b1 + p1r)
__global__ void k_hact(const float* __restrict__ agg1, const int* __restrict__ deg,
                       const float* __restrict__ b1, const float* __restrict__ p1r,
                       float* __restrict__ h) {
    int i  = blockIdx.x * blockDim.x + threadIdx.x;
    int st = gridDim.x * blockDim.x;
    int total = NN * DH;
    for (; i < total; i += st) {
        int n = i >> 4;
        int d = i & 15;
        float c = fmaxf((float)deg[n], 1.0f);
        float v = agg1[i] / c + b1[d] + p1r[i];
        h[i] = fmaxf(v, 0.0f);
    }
}

// one 64-lane wave per node:
//   o[j] = (aggh[n]/max(deg,1)) @ W2l[:,j] + b2[j] + h[n] @ W2r[:,j]
//   out[n] = log_softmax(o)
__global__ void k_final(const float* __restrict__ aggh, const int* __restrict__ deg,
                        const float* __restrict__ h,
                        const float* __restrict__ W2l, const float* __restrict__ b2,
                        const float* __restrict__ W2r, float* __restrict__ out) {
    __shared__ float sW[2 * DH * NC + NC];  // W2l, W2r, b2
    for (int i = threadIdx.x; i < DH * NC; i += blockDim.x) {
        sW[i]           = W2l[i];
        sW[DH * NC + i] = W2r[i];
    }
    for (int i = threadIdx.x; i < NC; i += blockDim.x) sW[2 * DH * NC + i] = b2[i];
    __syncthreads();

    int lane = threadIdx.x & 63;
    long wave0  = ((long)blockIdx.x * blockDim.x + threadIdx.x) >> 6;
    long nwaves = ((long)gridDim.x * blockDim.x) >> 6;
    for (long n = wave0; n < NN; n += nwaves) {
        float inv = 1.0f / fmaxf((float)deg[n], 1.0f);
        float o = 0.0f;
        if (lane < NC) {
            o = sW[2 * DH * NC + lane];
            #pragma unroll
            for (int k = 0; k < DH; ++k) {
                float a = aggh[n * DH + k] * inv;  // broadcast within wave
                o = fmaf(a,             sW[k * NC + lane],           o);
                o = fmaf(h[n * DH + k], sW[DH * NC + k * NC + lane], o);
            }
        }
        // wave-wide max (lanes >= NC contribute -inf)
        float m = (lane < NC) ? o : -INFINITY;
        #pragma unroll
        for (int msk = 32; msk; msk >>= 1) m = fmaxf(m, __shfl_xor(m, msk));
        float ex = (lane < NC) ? expf(o - m) : 0.0f;
        float s = ex;
        #pragma unroll
        for (int msk = 32; msk; msk >>= 1) s += __shfl_xor(s, msk);
        if (lane < NC) out[n * NC + lane] = o - m - logf(s);
    }
}

// ---------------- launch ----------------

extern "C" void kernel_launch(void* const* d_in, const int* in_sizes, int n_in,
                              void* d_out, int out_size, void* d_ws, size_t ws_size,
                              hipStream_t stream) {
    const float* x   = (const float*)d_in[0];
    const int*   ei  = (const int*)d_in[1];   // [2, E] int32
    const float* W1l = (const float*)d_in[2];
    const float* b1  = (const float*)d_in[3];
    const float* W1r = (const float*)d_in[4];
    const float* W2l = (const float*)d_in[5];
    const float* b2  = (const float*)d_in[6];
    const float* W2r = (const float*)d_in[7];
    float* out = (float*)d_out;

    const int E = in_sizes[1] / 2;
    const int* src = ei;
    const int* dst = ei + E;

    // workspace layout (floats): deg(int N) | agg1(16N) | aggh(16N) | p1l(16N) | p1r(16N) | h(16N)
    float* ws   = (float*)d_ws;
    int*   deg  = (int*)ws;
    float* agg1 = ws + NN;
    float* aggh = agg1 + 16 * NN;
    float* p1l  = aggh + 16 * NN;
    float* p1r  = p1l + 16 * NN;
    float* h    = p1r + 16 * NN;

    // zero deg + agg1 + aggh (ws is poisoned to 0xAA before each call)
    k_zero<<<2048, 256, 0, stream>>>(ws, NN * 33);
    k_degree<<<2048, 256, 0, stream>>>(dst, E, deg);
    k_proj1<<<12500, 256, 0, stream>>>(x, W1l, W1r, p1l, p1r);
    k_scatter16<<<(E * 16 + 255) / 256, 256, 0, stream>>>(src, dst, E, p1l, agg1);
    k_hact<<<(NN * 16 + 255) / 256, 256, 0, stream>>>(agg1, deg, b1, p1r, h);
    k_scatter16<<<(E * 16 + 255) / 256, 256, 0, stream>>>(src, dst, E, h, aggh);
    k_final<<<25000, 256, 0, stream>>>(aggh, deg, h, W2l, b2, W2r, out);
}